// Round 11
// baseline (193.508 us; speedup 1.0000x reference)
//
#include <hip/hip_runtime.h>

typedef unsigned short u16;
typedef __bf16 bf16x8 __attribute__((ext_vector_type(8)));
typedef float f32x4 __attribute__((ext_vector_type(4)));
typedef u16 u16x8 __attribute__((ext_vector_type(8)));
typedef u16 u16x4 __attribute__((ext_vector_type(4)));

typedef const __attribute__((address_space(1))) void* as1_cvp;
typedef __attribute__((address_space(3))) void* as3_vp;

__device__ __forceinline__ void async_cp16(const void* g, void* l) {
  __builtin_amdgcn_global_load_lds((as1_cvp)g, (as3_vp)l, 16, 0, 0);
}

__device__ __forceinline__ u16 f2bf(float f) {
  union { float f; unsigned u; } x; x.f = f;
  unsigned r = x.u + 0x7fffu + ((x.u >> 16) & 1u);
  return (u16)(r >> 16);
}

__device__ __forceinline__ float bf2f(u16 v) {
  union { unsigned u; float f; } x; x.u = ((unsigned)v) << 16;
  return x.f;
}

__device__ __constant__ float c_lut[16] = {
  0.0f, 1.0f, -1.0f, 0.5f, -0.5f, 0.333333f, -0.333333f, 0.2f, -0.2f,
  0.142857f, -0.142857f, 0.090909f, -0.090909f, 0.076923f, -0.076923f, 0.0f };

// ---------------- fused prep A: cvt x -> bf16, maxabs(w_attn), maxabs(w_proj) ----
__global__ void prep_a(const float* __restrict__ wA, const float* __restrict__ wP,
                       const float* __restrict__ x, u16* __restrict__ xbf,
                       unsigned* __restrict__ scales) {
  const int bx = blockIdx.x;
  if (bx < 4096) {  // cvt 4194304 floats
    int i = bx * 1024 + threadIdx.x * 4;
    float4 v = *(const float4*)(x + i);
    u16x4 r; r.x = f2bf(v.x); r.y = f2bf(v.y); r.z = f2bf(v.z); r.w = f2bf(v.w);
    *(u16x4*)(xbf + i) = r;
    return;
  }
  const bool isA = bx < 4160;
  const float* w = isA ? wA : wP;
  const int n = isA ? 3145728 : 1048576;
  unsigned* o = scales + (isA ? 0 : 1);
  float m = 0.f;
  for (int i = ((bx - (isA ? 4096 : 4160)) * 256 + threadIdx.x) * 4; i < n; i += 65536) {
    float4 v = *(const float4*)(w + i);
    m = fmaxf(fmaxf(fabsf(v.x), fabsf(v.y)), fmaxf(fmaxf(fabsf(v.z), fabsf(v.w)), m));
  }
  for (int off = 32; off > 0; off >>= 1)
    m = fmaxf(m, __shfl_down(m, off, 64));
  __shared__ float sm[4];
  if ((threadIdx.x & 63) == 0) sm[threadIdx.x >> 6] = m;
  __syncthreads();
  if (threadIdx.x == 0) {
    m = fmaxf(fmaxf(sm[0], sm[1]), fmaxf(sm[2], sm[3]));
    atomicMax(o, __float_as_uint(m));  // nonneg floats: uint order == float order
  }
}

// ---------------- fused prep B: snap both weight matrices to LUT, emit bf16 ----
__global__ void prep_b(const float* __restrict__ wA, const float* __restrict__ wP,
                       u16* __restrict__ oA, u16* __restrict__ oP,
                       const unsigned* __restrict__ scales) {
  int i = (blockIdx.x * 256 + threadIdx.x) * 4;
  const float* w; u16* o; float scale;
  if (i < 3145728) { w = wA; o = oA; scale = __uint_as_float(scales[0]) + 1e-6f; }
  else { i -= 3145728; w = wP; o = oP; scale = __uint_as_float(scales[1]) + 1e-6f; }
  float4 v = *(const float4*)(w + i);
  float vv[4] = {v.x, v.y, v.z, v.w};
  u16x4 r;
#pragma unroll
  for (int e = 0; e < 4; e++) {
    float wn = vv[e] / scale;
    float best = 1e30f; int bi = 0;
#pragma unroll
    for (int jj = 0; jj < 16; jj++) {
      float d = fabsf(wn - c_lut[jj]);
      if (d < best) { best = d; bi = jj; }
    }
    r[e] = f2bf(c_lut[bi] * scale);
  }
  *(u16x4*)(o + i) = r;
}

// ---------------- unified GEMM: 128 x BN tile, BK=32, RING-2, 2+ blocks/CU ----
// Round 11: the r0-r8 schedule invariance is VOID — it was measured while
// staging over-fetch was the binding pipe (fixed by r10's XCD swizzle).  The
// never-tested cell: L2-local staging + counted-vmcnt + >=2 blocks/CU.  All
// scheduled variants so far used 128KB LDS = 1 block/CU (8 waves) — barrier
// stalls had nothing to fill them.  m97's 874TF came from ~3 blocks/CU
// implicit overlap (m114), not intra-block scheduling.  Ring 4->2 halves LDS:
// gemm1 64KB -> 2 blocks/CU; gemm2 32KB -> 4 blocks/CU.  Depth-1 prefetch is
// enough now that staging is L2-hit (~250cyc << ~900cyc MFMA phase).
// Per tile: [end-BAR sealed] stage(T+1) -> vmcnt(LPT) -> BAR -> reads(T) ->
// lgkm(0) -> MFMA -> BAR.  One block's gate stall is filled by the other's MFMA.
template<int BN>
__global__ __launch_bounds__(512, 2)
void gemm_fp(const u16* __restrict__ A, const u16* __restrict__ B,
             const float* __restrict__ bias, u16* __restrict__ qk,
             u16* __restrict__ vT, float* __restrict__ outf, int K) {
  constexpr int NF = BN / 64;    // col frags per wave (6 or 2)
  constexpr int BJ = BN / 128;   // B 128-row groups (3 or 1)
  __shared__ __align__(16) u16 lds[8192 + 2 * BN * 32];  // A ring(2) | B ring(2)
  const int t = threadIdx.x;
  const int lane = t & 63, w = t >> 6;
  const int wm = w >> 2, wn = w & 3;
  const int quad = lane >> 4, l16 = lane & 15;
  // XCD swizzle (grid 8x32; dispatch round-robins linear id over 8 XCDs):
  // xcd = lin&7 owns a 4x8 sub-grid -> per-XCD working set ~5MB ~ L2.
  const int lin = blockIdx.x + 8 * blockIdx.y;
  const int xcd = lin & 7, slot = lin >> 3;
  const int bx = ((xcd & 1) << 2) | (slot & 3);
  const int by = ((xcd >> 1) << 3) | (slot >> 2);
  const int m0 = by * 128, n0 = bx * BN;
  const int KI = K >> 5;  // 32

  const int srow = t >> 2;                              // 0..127
  const int scol = ((t & 3) ^ ((t >> 3) & 3)) * 8;      // pre-swizzled source chunk
  const int cswz = (quad ^ ((l16 >> 1) & 3)) * 8;       // read-side swizzle
  const int aoff = (wm * 64 + l16) * 32 + cswz;
  const int boff = (wn * (BN / 4) + l16) * 32 + cswz;

  auto stage = [&](int kt) {
    const int bsel = kt & 1;
    async_cp16(A + (size_t)(m0 + srow) * K + kt * 32 + scol,
               lds + bsel * 4096 + t * 8);
#pragma unroll
    for (int j = 0; j < BJ; j++)
      async_cp16(B + (size_t)(n0 + j * 128 + srow) * K + kt * 32 + scol,
                 lds + 8192 + bsel * (BN * 32) + j * 4096 + t * 8);
  };

  f32x4 acc[4][NF] = {};
  stage(0);

  for (int kt = 0; kt < KI; kt++) {
    // buf[(kt+1)&1] was sealed by the end-barrier of iter kt-1 -> safe to stage
    if (kt + 1 < KI) {
      stage(kt + 1);
      if constexpr (BJ == 3) asm volatile("s_waitcnt vmcnt(4)" ::: "memory");
      else                   asm volatile("s_waitcnt vmcnt(2)" ::: "memory");
    } else {
      asm volatile("s_waitcnt vmcnt(0)" ::: "memory");
    }
    __builtin_amdgcn_s_barrier();        // all waves gated -> tile kt resident
    __builtin_amdgcn_sched_barrier(0);
    const u16* Ab = lds + (kt & 1) * 4096;
    const u16* Bb = lds + 8192 + (kt & 1) * (BN * 32);
    bf16x8 af[4], bfr[NF];
#pragma unroll
    for (int mf = 0; mf < 4; mf++) af[mf] = *(const bf16x8*)&Ab[aoff + mf * 512];
#pragma unroll
    for (int nf = 0; nf < NF; nf++) bfr[nf] = *(const bf16x8*)&Bb[boff + nf * 512];
    asm volatile("s_waitcnt lgkmcnt(0)" ::: "memory");
    __builtin_amdgcn_sched_barrier(0);
    __builtin_amdgcn_s_setprio(1);
#pragma unroll
    for (int mf = 0; mf < 4; mf++)
#pragma unroll
      for (int nf = 0; nf < NF; nf++)
        acc[mf][nf] = __builtin_amdgcn_mfma_f32_16x16x32_bf16(af[mf], bfr[nf], acc[mf][nf], 0, 0, 0);
    __builtin_amdgcn_s_setprio(0);
    __builtin_amdgcn_s_barrier();        // seal reads of buf[kt&1]
    __builtin_amdgcn_sched_barrier(0);
  }

  float bb[NF];
#pragma unroll
  for (int nf = 0; nf < NF; nf++) bb[nf] = bias[n0 + wn * (BN / 4) + nf * 16 + l16];
#pragma unroll
  for (int mf = 0; mf < 4; mf++) {
    const int rowb = m0 + wm * 64 + mf * 16 + quad * 4;
#pragma unroll
    for (int nf = 0; nf < NF; nf++) {
      const int colb = n0 + wn * (BN / 4) + nf * 16;   // lane-uniform region select
      const int col = colb + l16;
      if constexpr (BN == 384) {   // gemm1: Q (scaled) / K / V (transposed)
        if (colb >= 2048) {
          u16x4 pk;
#pragma unroll
          for (int r = 0; r < 4; r++) pk[r] = f2bf(acc[mf][nf][r] + bb[nf]);
          *(u16x4*)&vT[(size_t)(rowb >> 11) * 2097152 + (size_t)(col - 2048) * 2048 + (rowb & 2047)] = pk;
        } else {
          const float mult = (colb < 1024) ? 0.180336880f : 1.0f;   // log2(e)/8
#pragma unroll
          for (int r = 0; r < 4; r++)
            qk[(size_t)(rowb + r) * 2048 + col] = f2bf((acc[mf][nf][r] + bb[nf]) * mult);
        }
      } else {                     // gemm2: float out, ldc = 1024
#pragma unroll
        for (int r = 0; r < 4; r++)
          outf[(size_t)(rowb + r) * 1024 + col] = acc[mf][nf][r] + bb[nf];
      }
    }
  }
}

// ---------------- causal flash attention, uniform split-kv ----------------
// SWAPPED QK^T: s = mfma(K_frag, Q_frag) -> lane holds q = l16 fixed, 4
// consecutive kv per fragment -> P-store is 8x ds_write_b64 (no scatter).
__device__ __forceinline__ void do_visit(
    const u16* sKc, const u16* sVc, u16* sP, const bf16x8 (&aq)[2][2],
    f32x4 (&acc)[2][4], f32x4 (&accl)[2], bf16x8 onesf,
    int kv0, int qt, int w, int quad, int l16, int ph) {
  const int wrow0 = qt * 128 + w * 32;
  if (kv0 > wrow0 + 31) return;  // wave fully masked in this tile
  f32x4 s[4][2] = {};            // [kv-frag][q-frag]
#pragma unroll
  for (int ks = 0; ks < 2; ks++) {
#pragma unroll
    for (int kf = 0; kf < 4; kf++) {
      bf16x8 bk = *(const bf16x8*)&sKc[(kf * 16 + l16) * 64 + ((ks * 4 + quad) ^ ph) * 8];
#pragma unroll
      for (int qf = 0; qf < 2; qf++)
        s[kf][qf] = __builtin_amdgcn_mfma_f32_16x16x32_bf16(bk, aq[qf][ks], s[kf][qf], 0, 0, 0);
    }
  }
  if (kv0 + 63 > wrow0) {  // diagonal region: causal mask (kv > q)
#pragma unroll
    for (int kf = 0; kf < 4; kf++)
#pragma unroll
      for (int qf = 0; qf < 2; qf++)
#pragma unroll
        for (int r = 0; r < 4; r++)
          if ((kv0 + kf * 16 + quad * 4 + r) > (wrow0 + qf * 16 + l16)) s[kf][qf][r] = -1e30f;
  }
#pragma unroll
  for (int kf = 0; kf < 4; kf++)
#pragma unroll
    for (int qf = 0; qf < 2; qf++) {
      u16x4 pk;
#pragma unroll
      for (int r = 0; r < 4; r++) {
        float p = __builtin_amdgcn_exp2f(s[kf][qf][r]);
        pk[r] = (u16)(__float_as_uint(p) >> 16);
      }
      *(u16x4*)&sP[(w * 32 + qf * 16 + l16) * 72 + kf * 16 + quad * 4] = pk;
    }
  __asm__ volatile("s_waitcnt lgkmcnt(0)" ::: "memory");  // sP rows wave-private
#pragma unroll
  for (int ks = 0; ks < 2; ks++) {
#pragma unroll
    for (int mi = 0; mi < 2; mi++) {
      bf16x8 ap = *(const bf16x8*)&sP[(w * 32 + mi * 16 + l16) * 72 + ks * 32 + quad * 8];
#pragma unroll
      for (int ni = 0; ni < 4; ni++) {
        bf16x8 bv = *(const bf16x8*)&sVc[(ni * 16 + l16) * 64 + ((ks * 4 + quad) ^ ph) * 8];
        acc[mi][ni] = __builtin_amdgcn_mfma_f32_16x16x32_bf16(ap, bv, acc[mi][ni], 0, 0, 0);
      }
      accl[mi] = __builtin_amdgcn_mfma_f32_16x16x32_bf16(ap, onesf, accl[mi], 0, 0, 0);
    }
  }
}

__device__ __forceinline__ void epilogue_tile(
    const f32x4 (&acc)[2][4], const f32x4 (&accl)[2], int qt, int b, int h,
    u16* __restrict__ O, float* __restrict__ L, int w, int quad, int l16) {
#pragma unroll
  for (int mi = 0; mi < 2; mi++)
#pragma unroll
    for (int r = 0; r < 4; r++) {
      const int q = qt * 128 + w * 32 + mi * 16 + quad * 4 + r;
      const size_t orow = (size_t)(b * 2048 + q) * 1024 + h * 64;
#pragma unroll
      for (int ni = 0; ni < 4; ni++)
        O[orow + ni * 16 + l16] = f2bf(acc[mi][ni][r]);
      if (l16 == 0) L[(b * 16 + h) * 2048 + q] = accl[mi][r];
    }
}

// Counted-vmcnt visit gate (r9) + XCD swizzle (r10): each XCD owns 4
// consecutive bh values -> per-XCD K/V+Q ~3MB, L2-resident.
__global__ __launch_bounds__(256, 2)
void attn_kernel(const u16* __restrict__ qk, const u16* __restrict__ vT,
                 u16* __restrict__ O0, u16* __restrict__ O1,
                 float* __restrict__ L0, float* __restrict__ L1) {
  __shared__ __align__(16) u16 lds[32768];
  u16* const sK  = lds;
  u16* const sVt = lds + 8192;
  u16* const sQ  = lds + 16384;
  u16* const sP  = lds + 16384;

  const int t = threadIdx.x;
  const int lane = t & 63, w = t >> 6;
  const int quad = lane >> 4, l16 = lane & 15;
  const int ph = l16 & 7;
  // XCD swizzle: grid (16,32); xcd = lin&7 gets bh in [4*xcd..4*xcd+3], all x.
  const int lin = blockIdx.x + 16 * blockIdx.y;
  const int xcd = lin & 7, slot = lin >> 3;     // slot 0..63
  const int bxs = slot & 15;                    // (pair,half)
  const int bh  = (xcd << 2) | (slot >> 4);     // 4 heads per XCD
  const int pair = bxs >> 1, half = bxs & 1;
  const int qtB = 15 - pair, qtA = pair;
  const int nB = 16 - pair, nA = pair + 1;       // nB + nA = 17
  const int startB = half * nB, startA = half * nA;
  const int b = bh >> 4, h = bh & 15;

  const size_t qkbase = (size_t)(b * 2048) * 2048 + h * 64;
  const size_t vtbase = ((size_t)(b * 1024 + h * 64)) * 2048;
  const int srow = t >> 3, schunk = t & 7;

  auto prefetch = [&](int j, int buf) {
    const int kv1 = j * 64;
#pragma unroll
    for (int i = 0; i < 2; i++) {
      int row = i * 32 + srow;
      int colk = 1024 + (schunk ^ (row & 7)) * 8;
      async_cp16(qk + qkbase + (size_t)(kv1 + row) * 2048 + colk, sK + buf + i * 2048 + t * 8);
    }
#pragma unroll
    for (int i = 0; i < 2; i++) {
      int d = i * 32 + srow;
      int colv = kv1 + (schunk ^ (d & 7)) * 8;
      async_cp16(vT + vtbase + (size_t)d * 2048 + colv, sVt + buf + i * 2048 + t * 8);
    }
  };

#pragma unroll
  for (int tile = 0; tile < 2; tile++) {
    const int q0 = (tile ? qtA : qtB) * 128;
#pragma unroll
    for (int i = 0; i < 4; i++) {
      int row = i * 32 + srow;
      int col = (schunk ^ (row & 7)) * 8;
      async_cp16(qk + qkbase + (size_t)(q0 + row) * 2048 + col,
                 sQ + tile * 8192 + i * 2048 + t * 8);
    }
  }
  prefetch(startB, 0);
  __syncthreads();   // prologue drain: Q + tile 0 resident (vmcnt -> 0)

  bf16x8 aqB[2][2], aqA[2][2];
#pragma unroll
  for (int mi = 0; mi < 2; mi++)
#pragma unroll
    for (int ks = 0; ks < 2; ks++) {
      aqB[mi][ks] = *(const bf16x8*)&sQ[(w * 32 + mi * 16 + l16) * 64 + ((ks * 4 + quad) ^ ph) * 8];
      aqA[mi][ks] = *(const bf16x8*)&sQ[8192 + (w * 32 + mi * 16 + l16) * 64 + ((ks * 4 + quad) ^ ph) * 8];
    }
  __syncthreads();  // Q in regs everywhere; sP region writable

  f32x4 accB[2][4] = {}, accA[2][4] = {};
  f32x4 acclB[2] = {}, acclA[2] = {};
  u16x8 onesu = {};
  if (l16 == 0) {
#pragma unroll
    for (int i2 = 0; i2 < 8; i2++) onesu[i2] = 0x3F80;  // bf16 1.0
  }
  bf16x8 onesf = *(bf16x8*)&onesu;

  for (int v = 0; v < 17; v++) {
    const int cur = (v & 1) * 4096;
    if (v + 1 < 17) {
      const int jn = (v + 1 < nB) ? (startB + v + 1) : (startA + (v + 1 - nB));
      prefetch(jn, ((v + 1) & 1) * 4096);   // into buf sealed at end of v-1
      asm volatile("s_waitcnt vmcnt(4)" ::: "memory");   // tile v retired
    } else {
      asm volatile("s_waitcnt vmcnt(0)" ::: "memory");
    }
    __builtin_amdgcn_s_barrier();           // all gates passed -> tile v resident
    __builtin_amdgcn_sched_barrier(0);
    if (v < nB)
      do_visit(sK + cur, sVt + cur, sP, aqB, accB, acclB, onesf,
               (startB + v) * 64, qtB, w, quad, l16, ph);
    else
      do_visit(sK + cur, sVt + cur, sP, aqA, accA, acclA, onesf,
               (startA + v - nB) * 64, qtA, w, quad, l16, ph);
    __builtin_amdgcn_s_barrier();           // seal buf[v&1] reads
  }

  u16* Op = half ? O1 : O0;
  float* Lp = half ? L1 : L0;
  epilogue_tile(accB, acclB, qtB, b, h, Op, Lp, w, quad, l16);
  epilogue_tile(accA, acclA, qtA, b, h, Op, Lp, w, quad, l16);
}

// ---------------- combine partials: y = (O0+O1)/(l0+l1), in place over O1 ----
__global__ void norm_kernel(const u16* __restrict__ O0, u16* __restrict__ O1y,
                            const float* __restrict__ L0, const float* __restrict__ L1) {
  const int i = (blockIdx.x * 256 + threadIdx.x) * 8;
  const int row = i >> 10, col = i & 1023;
  const int b = row >> 11, q = row & 2047, h = col >> 6;
  const int li = (b * 16 + h) * 2048 + q;
  const float inv = 1.0f / (L0[li] + L1[li]);
  u16x8 a = *(const u16x8*)(O0 + i);
  u16x8 c = *(const u16x8*)(O1y + i);
  u16x8 r;
#pragma unroll
  for (int e = 0; e < 8; e++)
    r[e] = f2bf((bf2f(a[e]) + bf2f(c[e])) * inv);
  *(u16x8*)(O1y + i) = r;
}

extern "C" void kernel_launch(void* const* d_in, const int* in_sizes, int n_in,
                              void* d_out, int out_size, void* d_ws, size_t ws_size,
                              hipStream_t stream) {
  const float* x      = (const float*)d_in[0];
  const float* w_attn = (const float*)d_in[1];
  const float* b_attn = (const float*)d_in[2];
  const float* w_proj = (const float*)d_in[3];
  const float* b_proj = (const float*)d_in[4];
  float* out = (float*)d_out;

  char* ws = (char*)d_ws;
  unsigned* scales = (unsigned*)ws;
  u16* wAq = (u16*)(ws + 64);
  u16* wPq = (u16*)(ws + 64 + 6291456);
  u16* xbf = (u16*)(ws + 64 + 6291456 + 2097152);
  u16* qk  = (u16*)(ws + 64 + 6291456 + 2097152 + 8388608);
  u16* ybf = (u16*)(ws + 64 + 6291456 + 2097152 + 8388608 + 16777216);
  u16* vT  = (u16*)(ws + 64 + 6291456 + 2097152 + 8388608 + 16777216 + 8388608);

  u16* O0 = xbf;
  u16* O1 = ybf;
  float* L0 = (float*)(ws + 64);
  float* L1 = (float*)(ws + 64 + 1048576);

  (void)hipMemsetAsync(ws, 0, 8, stream);
  prep_a<<<4224, 256, 0, stream>>>(w_attn, w_proj, x, xbf, scales);
  prep_b<<<4096, 256, 0, stream>>>(w_attn, w_proj, wAq, wPq, scales);

  dim3 g1(8, 32);    // N=3072/384, M=4096/128 -> 256 blocks = exact CU fill
  gemm_fp<384><<<g1, 512, 0, stream>>>(xbf, wAq, b_attn, qk, vT, nullptr, 1024);

  dim3 ga(16, 32);   // (pair,half) x (b,h): 512 uniform blocks, 17 visits each
  attn_kernel<<<ga, 256, 0, stream>>>(qk, vT, O0, O1, L0, L1);
  norm_kernel<<<2048, 256, 0, stream>>>(O0, O1, L0, L1);

  dim3 g2(8, 32);    // N=1024/128, M=4096/128 -> 256 blocks = exact CU fill
  gemm_fp<128><<<g2, 512, 0, stream>>>(ybf, wPq, b_proj, nullptr, nullptr, out, 1024);
}

// Round 12
// 186.858 us; speedup vs baseline: 1.0356x; 1.0356x over previous
//
#include <hip/hip_runtime.h>

typedef unsigned short u16;
typedef __bf16 bf16x8 __attribute__((ext_vector_type(8)));
typedef float f32x4 __attribute__((ext_vector_type(4)));
typedef u16 u16x8 __attribute__((ext_vector_type(8)));
typedef u16 u16x4 __attribute__((ext_vector_type(4)));

typedef const __attribute__((address_space(1))) void* as1_cvp;
typedef __attribute__((address_space(3))) void* as3_vp;

__device__ __forceinline__ void async_cp16(const void* g, void* l) {
  __builtin_amdgcn_global_load_lds((as1_cvp)g, (as3_vp)l, 16, 0, 0);
}

__device__ __forceinline__ u16 f2bf(float f) {
  union { float f; unsigned u; } x; x.f = f;
  unsigned r = x.u + 0x7fffu + ((x.u >> 16) & 1u);
  return (u16)(r >> 16);
}

__device__ __forceinline__ float bf2f(u16 v) {
  union { unsigned u; float f; } x; x.u = ((unsigned)v) << 16;
  return x.f;
}

__device__ __constant__ float c_lut[16] = {
  0.0f, 1.0f, -1.0f, 0.5f, -0.5f, 0.333333f, -0.333333f, 0.2f, -0.2f,
  0.142857f, -0.142857f, 0.090909f, -0.090909f, 0.076923f, -0.076923f, 0.0f };

// ---------------- fused prep A: cvt x -> bf16, maxabs(w_attn), maxabs(w_proj) ----
__global__ void prep_a(const float* __restrict__ wA, const float* __restrict__ wP,
                       const float* __restrict__ x, u16* __restrict__ xbf,
                       unsigned* __restrict__ scales) {
  const int bx = blockIdx.x;
  if (bx < 4096) {  // cvt 4194304 floats
    int i = bx * 1024 + threadIdx.x * 4;
    float4 v = *(const float4*)(x + i);
    u16x4 r; r.x = f2bf(v.x); r.y = f2bf(v.y); r.z = f2bf(v.z); r.w = f2bf(v.w);
    *(u16x4*)(xbf + i) = r;
    return;
  }
  const bool isA = bx < 4160;
  const float* w = isA ? wA : wP;
  const int n = isA ? 3145728 : 1048576;
  unsigned* o = scales + (isA ? 0 : 1);
  float m = 0.f;
  for (int i = ((bx - (isA ? 4096 : 4160)) * 256 + threadIdx.x) * 4; i < n; i += 65536) {
    float4 v = *(const float4*)(w + i);
    m = fmaxf(fmaxf(fabsf(v.x), fabsf(v.y)), fmaxf(fmaxf(fabsf(v.z), fabsf(v.w)), m));
  }
  for (int off = 32; off > 0; off >>= 1)
    m = fmaxf(m, __shfl_down(m, off, 64));
  __shared__ float sm[4];
  if ((threadIdx.x & 63) == 0) sm[threadIdx.x >> 6] = m;
  __syncthreads();
  if (threadIdx.x == 0) {
    m = fmaxf(fmaxf(sm[0], sm[1]), fmaxf(sm[2], sm[3]));
    atomicMax(o, __float_as_uint(m));  // nonneg floats: uint order == float order
  }
}

// ---------------- fused prep B: snap both weight matrices to LUT, emit bf16 ----
__global__ void prep_b(const float* __restrict__ wA, const float* __restrict__ wP,
                       u16* __restrict__ oA, u16* __restrict__ oP,
                       const unsigned* __restrict__ scales) {
  int i = (blockIdx.x * 256 + threadIdx.x) * 4;
  const float* w; u16* o; float scale;
  if (i < 3145728) { w = wA; o = oA; scale = __uint_as_float(scales[0]) + 1e-6f; }
  else { i -= 3145728; w = wP; o = oP; scale = __uint_as_float(scales[1]) + 1e-6f; }
  float4 v = *(const float4*)(w + i);
  float vv[4] = {v.x, v.y, v.z, v.w};
  u16x4 r;
#pragma unroll
  for (int e = 0; e < 4; e++) {
    float wn = vv[e] / scale;
    float best = 1e30f; int bi = 0;
#pragma unroll
    for (int jj = 0; jj < 16; jj++) {
      float d = fabsf(wn - c_lut[jj]);
      if (d < best) { best = d; bi = jj; }
    }
    r[e] = f2bf(c_lut[bi] * scale);
  }
  *(u16x4*)(o + i) = r;
}

// ---------------- unified GEMM: 128 x BN tile, BK=32, ring-4, fine 2-phase ----
// r12 = exact r10 restore (best measured, 188.7us).  Staging-locality fix:
// bijective XCD swizzle, each XCD owns a 4x8 sub-grid -> per-XCD working set
// ~5MB ~ L2 -> L2-resident staging (FETCH was 38MB vs 14MB unique before).
// Schedule: ring-4, counted vmcnt gates, fine 2-phase (proven best of 9
// structural variants r0-r11; ring-2/2-blocks-per-CU was null, r11).
template<int BN>
__global__ __launch_bounds__(512, 2)
void gemm_fp(const u16* __restrict__ A, const u16* __restrict__ B,
             const float* __restrict__ bias, u16* __restrict__ qk,
             u16* __restrict__ vT, float* __restrict__ outf, int K) {
  constexpr int NF = BN / 64;    // col frags per wave (6 or 2)
  constexpr int BJ = BN / 128;   // B 128-row groups (3 or 1)
  constexpr int NH = NF / 2;     // frags per phase
  __shared__ __align__(16) u16 lds[16384 + BN * 32 * 4];  // A ring | B ring
  const int t = threadIdx.x;
  const int lane = t & 63, w = t >> 6;
  const int wm = w >> 2, wn = w & 3;
  const int quad = lane >> 4, l16 = lane & 15;
  // XCD swizzle (grid fixed 8x32; dispatch round-robins linear id over 8 XCDs):
  // xcd = lin&7 gets blocks {bx in 4*(xcd&1)..+3} x {by in 8*(xcd>>1)..+7}.
  const int lin = blockIdx.x + 8 * blockIdx.y;
  const int xcd = lin & 7, slot = lin >> 3;
  const int bx = ((xcd & 1) << 2) | (slot & 3);
  const int by = ((xcd >> 1) << 3) | (slot >> 2);
  const int m0 = by * 128, n0 = bx * BN;
  const int KI = K >> 5;  // 32

  const int srow = t >> 2;                              // 0..127
  const int scol = ((t & 3) ^ ((t >> 3) & 3)) * 8;      // pre-swizzled source chunk
  const int cswz = (quad ^ ((l16 >> 1) & 3)) * 8;       // read-side swizzle
  const int aoff = (wm * 64 + l16) * 32 + cswz;
  const int boff = (wn * (BN / 4) + l16) * 32 + cswz;

  auto stageA = [&](int kt) {
    async_cp16(A + (size_t)(m0 + srow) * K + kt * 32 + scol,
               lds + (kt & 3) * 4096 + t * 8);
  };
  auto stageB = [&](int kt, int j) {
    async_cp16(B + (size_t)(n0 + j * 128 + srow) * K + kt * 32 + scol,
               lds + 16384 + (kt & 3) * (BN * 32) + j * 4096 + t * 8);
  };

  f32x4 acc[4][NF] = {};
#pragma unroll
  for (int p = 0; p < 3; p++) {
    stageA(p);
#pragma unroll
    for (int j = 0; j < BJ; j++) stageB(p, j);
  }

  for (int kt = 0; kt < KI; kt++) {
    const u16* Ab = lds + (kt & 3) * 4096;
    const u16* Bb = lds + 16384 + (kt & 3) * (BN * 32);
    bf16x8 af[4], bfr[NF];
    if (kt < KI - 2) {
      if constexpr (BJ == 3) asm volatile("s_waitcnt vmcnt(8)" ::: "memory");
      else                   asm volatile("s_waitcnt vmcnt(4)" ::: "memory");
    } else if (kt == KI - 2) {
      if constexpr (BJ == 3) asm volatile("s_waitcnt vmcnt(4)" ::: "memory");
      else                   asm volatile("s_waitcnt vmcnt(2)" ::: "memory");
    } else {
      asm volatile("s_waitcnt vmcnt(0)" ::: "memory");
    }
    __builtin_amdgcn_s_barrier();
    __builtin_amdgcn_sched_barrier(0);
#pragma unroll
    for (int mf = 0; mf < 4; mf++) af[mf] = *(const bf16x8*)&Ab[aoff + mf * 512];
#pragma unroll
    for (int nf = 0; nf < NH; nf++) bfr[nf] = *(const bf16x8*)&Bb[boff + nf * 512];
    if (kt + 3 < KI) {
      stageA(kt + 3);
      if constexpr (BJ == 3) stageB(kt + 3, 0);
    }
    asm volatile("s_waitcnt lgkmcnt(0)" ::: "memory");
    __builtin_amdgcn_sched_barrier(0);
    __builtin_amdgcn_s_setprio(1);
#pragma unroll
    for (int mf = 0; mf < 4; mf++)
#pragma unroll
      for (int nf = 0; nf < NH; nf++)
        acc[mf][nf] = __builtin_amdgcn_mfma_f32_16x16x32_bf16(af[mf], bfr[nf], acc[mf][nf], 0, 0, 0);
    __builtin_amdgcn_s_setprio(0);
    __builtin_amdgcn_s_barrier();
    __builtin_amdgcn_sched_barrier(0);
#pragma unroll
    for (int nf = NH; nf < NF; nf++) bfr[nf] = *(const bf16x8*)&Bb[boff + nf * 512];
    if (kt + 3 < KI) {
      if constexpr (BJ == 3) { stageB(kt + 3, 1); stageB(kt + 3, 2); }
      else                   stageB(kt + 3, 0);
    }
    asm volatile("s_waitcnt lgkmcnt(0)" ::: "memory");
    __builtin_amdgcn_sched_barrier(0);
    __builtin_amdgcn_s_setprio(1);
#pragma unroll
    for (int mf = 0; mf < 4; mf++)
#pragma unroll
      for (int nf = NH; nf < NF; nf++)
        acc[mf][nf] = __builtin_amdgcn_mfma_f32_16x16x32_bf16(af[mf], bfr[nf], acc[mf][nf], 0, 0, 0);
    __builtin_amdgcn_s_setprio(0);
  }

  float bb[NF];
#pragma unroll
  for (int nf = 0; nf < NF; nf++) bb[nf] = bias[n0 + wn * (BN / 4) + nf * 16 + l16];
#pragma unroll
  for (int mf = 0; mf < 4; mf++) {
    const int rowb = m0 + wm * 64 + mf * 16 + quad * 4;
#pragma unroll
    for (int nf = 0; nf < NF; nf++) {
      const int colb = n0 + wn * (BN / 4) + nf * 16;   // lane-uniform region select
      const int col = colb + l16;
      if constexpr (BN == 384) {   // gemm1: Q (scaled) / K / V (transposed)
        if (colb >= 2048) {
          u16x4 pk;
#pragma unroll
          for (int r = 0; r < 4; r++) pk[r] = f2bf(acc[mf][nf][r] + bb[nf]);
          *(u16x4*)&vT[(size_t)(rowb >> 11) * 2097152 + (size_t)(col - 2048) * 2048 + (rowb & 2047)] = pk;
        } else {
          const float mult = (colb < 1024) ? 0.180336880f : 1.0f;   // log2(e)/8
#pragma unroll
          for (int r = 0; r < 4; r++)
            qk[(size_t)(rowb + r) * 2048 + col] = f2bf((acc[mf][nf][r] + bb[nf]) * mult);
        }
      } else {                     // gemm2: float out, ldc = 1024
#pragma unroll
        for (int r = 0; r < 4; r++)
          outf[(size_t)(rowb + r) * 1024 + col] = acc[mf][nf][r] + bb[nf];
      }
    }
  }
}

// ---------------- causal flash attention, uniform split-kv ----------------
// SWAPPED QK^T: s = mfma(K_frag, Q_frag) -> lane holds q = l16 fixed, 4
// consecutive kv per fragment -> P-store is 8x ds_write_b64 (no scatter).
__device__ __forceinline__ void do_visit(
    const u16* sKc, const u16* sVc, u16* sP, const bf16x8 (&aq)[2][2],
    f32x4 (&acc)[2][4], f32x4 (&accl)[2], bf16x8 onesf,
    int kv0, int qt, int w, int quad, int l16, int ph) {
  const int wrow0 = qt * 128 + w * 32;
  if (kv0 > wrow0 + 31) return;  // wave fully masked in this tile
  f32x4 s[4][2] = {};            // [kv-frag][q-frag]
#pragma unroll
  for (int ks = 0; ks < 2; ks++) {
#pragma unroll
    for (int kf = 0; kf < 4; kf++) {
      bf16x8 bk = *(const bf16x8*)&sKc[(kf * 16 + l16) * 64 + ((ks * 4 + quad) ^ ph) * 8];
#pragma unroll
      for (int qf = 0; qf < 2; qf++)
        s[kf][qf] = __builtin_amdgcn_mfma_f32_16x16x32_bf16(bk, aq[qf][ks], s[kf][qf], 0, 0, 0);
    }
  }
  if (kv0 + 63 > wrow0) {  // diagonal region: causal mask (kv > q)
#pragma unroll
    for (int kf = 0; kf < 4; kf++)
#pragma unroll
      for (int qf = 0; qf < 2; qf++)
#pragma unroll
        for (int r = 0; r < 4; r++)
          if ((kv0 + kf * 16 + quad * 4 + r) > (wrow0 + qf * 16 + l16)) s[kf][qf][r] = -1e30f;
  }
#pragma unroll
  for (int kf = 0; kf < 4; kf++)
#pragma unroll
    for (int qf = 0; qf < 2; qf++) {
      u16x4 pk;
#pragma unroll
      for (int r = 0; r < 4; r++) {
        float p = __builtin_amdgcn_exp2f(s[kf][qf][r]);
        pk[r] = (u16)(__float_as_uint(p) >> 16);
      }
      *(u16x4*)&sP[(w * 32 + qf * 16 + l16) * 72 + kf * 16 + quad * 4] = pk;
    }
  __asm__ volatile("s_waitcnt lgkmcnt(0)" ::: "memory");  // sP rows wave-private
#pragma unroll
  for (int ks = 0; ks < 2; ks++) {
#pragma unroll
    for (int mi = 0; mi < 2; mi++) {
      bf16x8 ap = *(const bf16x8*)&sP[(w * 32 + mi * 16 + l16) * 72 + ks * 32 + quad * 8];
#pragma unroll
      for (int ni = 0; ni < 4; ni++) {
        bf16x8 bv = *(const bf16x8*)&sVc[(ni * 16 + l16) * 64 + ((ks * 4 + quad) ^ ph) * 8];
        acc[mi][ni] = __builtin_amdgcn_mfma_f32_16x16x32_bf16(ap, bv, acc[mi][ni], 0, 0, 0);
      }
      accl[mi] = __builtin_amdgcn_mfma_f32_16x16x32_bf16(ap, onesf, accl[mi], 0, 0, 0);
    }
  }
}

__device__ __forceinline__ void epilogue_tile(
    const f32x4 (&acc)[2][4], const f32x4 (&accl)[2], int qt, int b, int h,
    u16* __restrict__ O, float* __restrict__ L, int w, int quad, int l16) {
#pragma unroll
  for (int mi = 0; mi < 2; mi++)
#pragma unroll
    for (int r = 0; r < 4; r++) {
      const int q = qt * 128 + w * 32 + mi * 16 + quad * 4 + r;
      const size_t orow = (size_t)(b * 2048 + q) * 1024 + h * 64;
#pragma unroll
      for (int ni = 0; ni < 4; ni++)
        O[orow + ni * 16 + l16] = f2bf(acc[mi][ni][r]);
      if (l16 == 0) L[(b * 16 + h) * 2048 + q] = accl[mi][r];
    }
}

// Counted-vmcnt visit gate (r9) + XCD swizzle (r10): each XCD owns 4
// consecutive bh values -> per-XCD K/V+Q ~3MB, L2-resident.
__global__ __launch_bounds__(256, 2)
void attn_kernel(const u16* __restrict__ qk, const u16* __restrict__ vT,
                 u16* __restrict__ O0, u16* __restrict__ O1,
                 float* __restrict__ L0, float* __restrict__ L1) {
  __shared__ __align__(16) u16 lds[32768];
  u16* const sK  = lds;
  u16* const sVt = lds + 8192;
  u16* const sQ  = lds + 16384;
  u16* const sP  = lds + 16384;

  const int t = threadIdx.x;
  const int lane = t & 63, w = t >> 6;
  const int quad = lane >> 4, l16 = lane & 15;
  const int ph = l16 & 7;
  // XCD swizzle: grid (16,32); xcd = lin&7 gets bh in [4*xcd..4*xcd+3], all x.
  const int lin = blockIdx.x + 16 * blockIdx.y;
  const int xcd = lin & 7, slot = lin >> 3;     // slot 0..63
  const int bxs = slot & 15;                    // (pair,half)
  const int bh  = (xcd << 2) | (slot >> 4);     // 4 heads per XCD
  const int pair = bxs >> 1, half = bxs & 1;
  const int qtB = 15 - pair, qtA = pair;
  const int nB = 16 - pair, nA = pair + 1;       // nB + nA = 17
  const int startB = half * nB, startA = half * nA;
  const int b = bh >> 4, h = bh & 15;

  const size_t qkbase = (size_t)(b * 2048) * 2048 + h * 64;
  const size_t vtbase = ((size_t)(b * 1024 + h * 64)) * 2048;
  const int srow = t >> 3, schunk = t & 7;

  auto prefetch = [&](int j, int buf) {
    const int kv1 = j * 64;
#pragma unroll
    for (int i = 0; i < 2; i++) {
      int row = i * 32 + srow;
      int colk = 1024 + (schunk ^ (row & 7)) * 8;
      async_cp16(qk + qkbase + (size_t)(kv1 + row) * 2048 + colk, sK + buf + i * 2048 + t * 8);
    }
#pragma unroll
    for (int i = 0; i < 2; i++) {
      int d = i * 32 + srow;
      int colv = kv1 + (schunk ^ (d & 7)) * 8;
      async_cp16(vT + vtbase + (size_t)d * 2048 + colv, sVt + buf + i * 2048 + t * 8);
    }
  };

#pragma unroll
  for (int tile = 0; tile < 2; tile++) {
    const int q0 = (tile ? qtA : qtB) * 128;
#pragma unroll
    for (int i = 0; i < 4; i++) {
      int row = i * 32 + srow;
      int col = (schunk ^ (row & 7)) * 8;
      async_cp16(qk + qkbase + (size_t)(q0 + row) * 2048 + col,
                 sQ + tile * 8192 + i * 2048 + t * 8);
    }
  }
  prefetch(startB, 0);
  __syncthreads();   // prologue drain: Q + tile 0 resident (vmcnt -> 0)

  bf16x8 aqB[2][2], aqA[2][2];
#pragma unroll
  for (int mi = 0; mi < 2; mi++)
#pragma unroll
    for (int ks = 0; ks < 2; ks++) {
      aqB[mi][ks] = *(const bf16x8*)&sQ[(w * 32 + mi * 16 + l16) * 64 + ((ks * 4 + quad) ^ ph) * 8];
      aqA[mi][ks] = *(const bf16x8*)&sQ[8192 + (w * 32 + mi * 16 + l16) * 64 + ((ks * 4 + quad) ^ ph) * 8];
    }
  __syncthreads();  // Q in regs everywhere; sP region writable

  f32x4 accB[2][4] = {}, accA[2][4] = {};
  f32x4 acclB[2] = {}, acclA[2] = {};
  u16x8 onesu = {};
  if (l16 == 0) {
#pragma unroll
    for (int i2 = 0; i2 < 8; i2++) onesu[i2] = 0x3F80;  // bf16 1.0
  }
  bf16x8 onesf = *(bf16x8*)&onesu;

  for (int v = 0; v < 17; v++) {
    const int cur = (v & 1) * 4096;
    if (v + 1 < 17) {
      const int jn = (v + 1 < nB) ? (startB + v + 1) : (startA + (v + 1 - nB));
      prefetch(jn, ((v + 1) & 1) * 4096);   // into buf sealed at end of v-1
      asm volatile("s_waitcnt vmcnt(4)" ::: "memory");   // tile v retired
    } else {
      asm volatile("s_waitcnt vmcnt(0)" ::: "memory");
    }
    __builtin_amdgcn_s_barrier();           // all gates passed -> tile v resident
    __builtin_amdgcn_sched_barrier(0);
    if (v < nB)
      do_visit(sK + cur, sVt + cur, sP, aqB, accB, acclB, onesf,
               (startB + v) * 64, qtB, w, quad, l16, ph);
    else
      do_visit(sK + cur, sVt + cur, sP, aqA, accA, acclA, onesf,
               (startA + v - nB) * 64, qtA, w, quad, l16, ph);
    __builtin_amdgcn_s_barrier();           // seal buf[v&1] reads
  }

  u16* Op = half ? O1 : O0;
  float* Lp = half ? L1 : L0;
  epilogue_tile(accB, acclB, qtB, b, h, Op, Lp, w, quad, l16);
  epilogue_tile(accA, acclA, qtA, b, h, Op, Lp, w, quad, l16);
}

// ---------------- combine partials: y = (O0+O1)/(l0+l1), in place over O1 ----
__global__ void norm_kernel(const u16* __restrict__ O0, u16* __restrict__ O1y,
                            const float* __restrict__ L0, const float* __restrict__ L1) {
  const int i = (blockIdx.x * 256 + threadIdx.x) * 8;
  const int row = i >> 10, col = i & 1023;
  const int b = row >> 11, q = row & 2047, h = col >> 6;
  const int li = (b * 16 + h) * 2048 + q;
  const float inv = 1.0f / (L0[li] + L1[li]);
  u16x8 a = *(const u16x8*)(O0 + i);
  u16x8 c = *(const u16x8*)(O1y + i);
  u16x8 r;
#pragma unroll
  for (int e = 0; e < 8; e++)
    r[e] = f2bf((bf2f(a[e]) + bf2f(c[e])) * inv);
  *(u16x8*)(O1y + i) = r;
}

extern "C" void kernel_launch(void* const* d_in, const int* in_sizes, int n_in,
                              void* d_out, int out_size, void* d_ws, size_t ws_size,
                              hipStream_t stream) {
  const float* x      = (const float*)d_in[0];
  const float* w_attn = (const float*)d_in[1];
  const float* b_attn = (const float*)d_in[2];
  const float* w_proj = (const float*)d_in[3];
  const float* b_proj = (const float*)d_in[4];
  float* out = (float*)d_out;

  char* ws = (char*)d_ws;
  unsigned* scales = (unsigned*)ws;
  u16* wAq = (u16*)(ws + 64);
  u16* wPq = (u16*)(ws + 64 + 6291456);
  u16* xbf = (u16*)(ws + 64 + 6291456 + 2097152);
  u16* qk  = (u16*)(ws + 64 + 6291456 + 2097152 + 8388608);
  u16* ybf = (u16*)(ws + 64 + 6291456 + 2097152 + 8388608 + 16777216);
  u16* vT  = (u16*)(ws + 64 + 6291456 + 2097152 + 8388608 + 16777216 + 8388608);

  u16* O0 = xbf;
  u16* O1 = ybf;
  float* L0 = (float*)(ws + 64);
  float* L1 = (float*)(ws + 64 + 1048576);

  (void)hipMemsetAsync(ws, 0, 8, stream);
  prep_a<<<4224, 256, 0, stream>>>(w_attn, w_proj, x, xbf, scales);
  prep_b<<<4096, 256, 0, stream>>>(w_attn, w_proj, wAq, wPq, scales);

  dim3 g1(8, 32);    // N=3072/384, M=4096/128 -> 256 blocks = exact CU fill
  gemm_fp<384><<<g1, 512, 0, stream>>>(xbf, wAq, b_attn, qk, vT, nullptr, 1024);

  dim3 ga(16, 32);   // (pair,half) x (b,h): 512 uniform blocks, 17 visits each
  attn_kernel<<<ga, 256, 0, stream>>>(qk, vT, O0, O1, L0, L1);
  norm_kernel<<<2048, 256, 0, stream>>>(O0, O1, L0, L1);

  dim3 g2(8, 32);    // N=1024/128, M=4096/128 -> 256 blocks = exact CU fill
  gemm_fp<128><<<g2, 512, 0, stream>>>(ybf, wPq, b_proj, nullptr, nullptr, out, 1024);
}